// Round 6
// baseline (3569.051 us; speedup 1.0000x reference)
//
#include <hip/hip_runtime.h>
#include <hip/hip_bf16.h>

// 3-layer GCN: bf16-MFMA GEMMs + neighbor aggregation.
//   hs = bf16( dinv[row] * (act(A) @ W) )     (MFMA GEMM, act = BN+ReLU fused)
//   y[i] = dinv[i]*(hs[i] + sum_{e: s->i} hs[s]) + b  (fp32 acc, bf16 out)
// Aggregate ledger:
//  r3-r13: gather ~93us plateau @512blk/4-node (256B rows).
//  r15: XCD-count invariant FETCH -> replication model refuted.
//  r16: XCD feature-split -> 76.8us. Win = single-128B-line requests + 2x
//       streams (BW 2.0 TB/s), not residency (87% miss).
//  r17: 2x grid: BW flat -> random-line ceiling ~16-17 G lines/s. Closed.
//  r18: src-sorted adjacency: null (+50us sort tax). REVERTED.
//  r19: partitioned scatter (src-CSR, XCD owns dst-quarter x feature-half,
//       L2-resident fp32 acc): CRASHED. Audit: fallback layout inserted sdeg
//       (+200KB) shifting the r2 footprint -> tail OOB if ws is tight; the
//       r19 path needs ~54.5MB and may never have run.
//  r20: REPAIR+DISCRIMINATE. Fallback = byte-exact r2 layout (nullable sdeg,
//       memset (512+n)*4). r19 path unchanged but gated ws>=need and with
//       defensive clamps (OOB -> wrong-answer, not SIGABRT).
//       Outcomes: tight ws -> 393us pass (r2 counters); big ws + correct ->
//       ~340-365us, scatter128 30-45us; big ws + bug -> finite absmax fail.

typedef __attribute__((ext_vector_type(8))) short short8;   // 8 bf16
typedef __attribute__((ext_vector_type(4))) float f32x4;    // 4 fp32 acc

__device__ inline unsigned short f2bf(float f) {  // round-to-nearest-even
    unsigned int u = __float_as_uint(f);
    return (unsigned short)((u + 0x7fff + ((u >> 16) & 1)) >> 16);
}
__device__ inline float bf2f_lo(unsigned int p) { return __uint_as_float(p << 16); }
__device__ inline float bf2f_hi(unsigned int p) { return __uint_as_float(p & 0xffff0000u); }

__device__ inline void bf4_acc(uint2 v, float* a) {
    a[0] += bf2f_lo(v.x); a[1] += bf2f_hi(v.x);
    a[2] += bf2f_lo(v.y); a[3] += bf2f_hi(v.y);
}

// ---- fused prep: deg (+optional sdeg) counts + x->bf16 + W->Wt bf16 ----
__global__ void prep_kernel(const int* __restrict__ src,
                            const int* __restrict__ dst, int E,
                            int* __restrict__ deg, int* __restrict__ sdeg,
                            const float* __restrict__ x,
                            unsigned short* __restrict__ xb, int total4,
                            const float* __restrict__ W1,
                            const float* __restrict__ W2,
                            const float* __restrict__ W3,
                            unsigned short* __restrict__ wt1,
                            unsigned short* __restrict__ wt2,
                            unsigned short* __restrict__ wt3,
                            int EB, int XB) {
    const int b = blockIdx.x;
    const int t = threadIdx.x;
    if (b < EB) {
        int e = b * 256 + t;
        if (e < E) {
            atomicAdd(deg + dst[e], 1);
            if (sdeg != nullptr) atomicAdd(sdeg + src[e], 1);
        }
    } else if (b < EB + XB) {
        int i = (b - EB) * 256 + t;
        if (i < total4) {
            float4 v = reinterpret_cast<const float4*>(x)[i];
            uint2 p;
            p.x = f2bf(v.x) | ((unsigned)f2bf(v.y) << 16);
            p.y = f2bf(v.z) | ((unsigned)f2bf(v.w) << 16);
            reinterpret_cast<uint2*>(xb)[i] = p;
        }
    } else if (b < EB + XB + 64) {
        int idx = (b - EB - XB) * 256 + t;   // 128x128
        int k = idx >> 7, nn = idx & 127;
        wt1[nn * 128 + k] = f2bf(W1[idx]);
    } else if (b < EB + XB + 128) {
        int idx = (b - EB - XB - 64) * 256 + t;
        int k = idx >> 7, nn = idx & 127;
        wt2[nn * 128 + k] = f2bf(W2[idx]);
    } else {
        int idx = (b - EB - XB - 128) * 256 + t;  // 128x64
        int k = idx >> 6, nn = idx & 63;
        wt3[nn * 128 + k] = f2bf(W3[idx]);
    }
}

// ================= NEW PATH (r19/r20): src-CSR + scatter =================

__global__ __launch_bounds__(256) void prescan2_kernel(
    const int* __restrict__ deg, const int* __restrict__ sdeg, int n,
    float* __restrict__ dinv, int* __restrict__ srcptr,
    int* __restrict__ bsum) {
    __shared__ int sh[256];
    const int t = threadIdx.x, b = blockIdx.x;
    const int base = b * 2048 + t * 8;
    int v[8];
    int run = 0;
#pragma unroll
    for (int j = 0; j < 8; ++j) {
        int idx = base + j;
        int d = 0;
        if (idx < n) {
            dinv[idx] = rsqrtf((float)(deg[idx] + 1));
            d = sdeg[idx];
        }
        run += d;
        v[j] = run;
    }
    sh[t] = run;
    __syncthreads();
#pragma unroll
    for (int off = 1; off < 256; off <<= 1) {
        int add = (t >= off) ? sh[t - off] : 0;
        __syncthreads();
        sh[t] += add;
        __syncthreads();
    }
    int prev = (t > 0) ? sh[t - 1] : 0;
#pragma unroll
    for (int j = 0; j < 8; ++j) {
        int idx = base + j;
        if (idx < n) srcptr[idx + 1] = v[j] + prev;
    }
    if (t == 255) bsum[b] = sh[255];
    if (b == 0 && t == 0) srcptr[0] = 0;
}

__global__ void midscan2_kernel(int* __restrict__ bsum, int B) {
    __shared__ int sh[64];
    const int t = threadIdx.x;
    int v = (t < B) ? bsum[t] : 0;
    sh[t] = v;
    __syncthreads();
#pragma unroll
    for (int off = 1; off < 64; off <<= 1) {
        int add = (t >= off) ? sh[t - off] : 0;
        __syncthreads();
        sh[t] += add;
        __syncthreads();
    }
    if (t < B) bsum[t] = sh[t];
}

__global__ void fixup_kernel(int n, const int* __restrict__ bsum,
                             int* __restrict__ srcptr) {
    const int c = blockIdx.x;
    if (c == 0) return;
    const int off = bsum[c - 1];
    const int lim = min((c + 1) * 2048, n);
    for (int i = c * 2048 + threadIdx.x; i < lim; i += 256)
        srcptr[i + 1] += off;
}

// destructive cursor placement: dsts grouped by src (defensive pos clamp)
__global__ void csc_build_kernel(const int* __restrict__ src,
                                 const int* __restrict__ dst, int E,
                                 int* __restrict__ srcptr,
                                 int* __restrict__ csc_dst) {
    int e = blockIdx.x * blockDim.x + threadIdx.x;
    if (e < E) {
        int pos = atomicAdd(srcptr + src[e], 1);
        if ((unsigned)pos < (unsigned)E) csc_dst[pos] = dst[e];
    }
}

// Partitioned scatter. XCD = blockIdx%8 [m09/m157].
// F=128: partition (dst-quarter = xcd&3, feature-half = xcd>>2).
// F=64:  partition dst-octant = xcd, all 64 features.
// Defensive clamps: any cursor/logic fault -> skipped work (absmax signal),
// never an illegal address.
template <int F>
__global__ __launch_bounds__(256) void scatter_kernel(
    const unsigned short* __restrict__ hs, const int* __restrict__ srcptr,
    const int* __restrict__ csc_dst, float* __restrict__ acc, int n, int E) {
    const int xcd = blockIdx.x & 7;
    const int wb = blockIdx.x >> 3;
    const int nwb = gridDim.x >> 3;
    int lo, hi, fb;
    if (F == 128) {
        const int q = xcd & 3, h = xcd >> 2;
        const int qs = (n + 3) >> 2;
        lo = q * qs; hi = min(lo + qs, n); fb = h * 64;
    } else {
        const int os = (n + 7) >> 3;
        lo = xcd * os; hi = min(lo + os, n); fb = 0;
    }
    const int lane = threadIdx.x & 15;
    const int grp = threadIdx.x >> 4;     // 16 groups/block
    const int s0 = wb * 16 + grp;
    const int ns = nwb * 16;              // streams per XCD

    for (int s = s0; s < n; s += ns) {
        int e0 = (s == 0) ? 0 : srcptr[s - 1];
        int e1 = srcptr[s];
        if (e0 < 0) e0 = 0;
        if (e1 > E) e1 = E;
        if (e0 >= e1) continue;
        uint2 hv = *reinterpret_cast<const uint2*>(
            hs + (size_t)s * F + fb + lane * 4);
        const float v0 = bf2f_lo(hv.x), v1 = bf2f_hi(hv.x);
        const float v2 = bf2f_lo(hv.y), v3 = bf2f_hi(hv.y);
        for (int e = e0; e < e1; ++e) {
            int d = csc_dst[e];
            if (d < lo || d >= hi) continue;   // also guards d out of [0,n)
            float* a = acc + (size_t)d * F + fb + lane * 4;
            atomicAdd(a + 0, v0);
            atomicAdd(a + 1, v1);
            atomicAdd(a + 2, v2);
            atomicAdd(a + 3, v3);
        }
    }
}

// finalize F=128: y = dinv*(hs_self + acc) + bias; bf16 out; BN stats
__global__ __launch_bounds__(256) void finalize128_kernel(
    const unsigned short* __restrict__ hs, const float* __restrict__ acc,
    const float* __restrict__ dinv, const float* __restrict__ bias,
    unsigned short* __restrict__ outb, int n, float* __restrict__ stats) {
    const int lane = threadIdx.x & 31;   // 32 lanes x 4 feats
    const int grp = threadIdx.x >> 5;    // 8 rows per pass
    const int fq = lane * 4;
    const float4 b4 = *reinterpret_cast<const float4*>(bias + fq);
    float s[4] = {}, sq[4] = {};

    for (int i = blockIdx.x * 8 + grp; i < n; i += gridDim.x * 8) {
        const float di = dinv[i];
        uint2 hv = *reinterpret_cast<const uint2*>(hs + (size_t)i * 128 + fq);
        float4 av = *reinterpret_cast<const float4*>(acc + (size_t)i * 128 + fq);
        float y[4];
        y[0] = fmaf(di, bf2f_lo(hv.x) + av.x, b4.x);
        y[1] = fmaf(di, bf2f_hi(hv.x) + av.y, b4.y);
        y[2] = fmaf(di, bf2f_lo(hv.y) + av.z, b4.z);
        y[3] = fmaf(di, bf2f_hi(hv.y) + av.w, b4.w);
        uint2 p;
        p.x = f2bf(y[0]) | ((unsigned)f2bf(y[1]) << 16);
        p.y = f2bf(y[2]) | ((unsigned)f2bf(y[3]) << 16);
        *reinterpret_cast<uint2*>(outb + (size_t)i * 128 + fq) = p;
#pragma unroll
        for (int j = 0; j < 4; ++j) {
            s[j] += y[j];
            sq[j] = fmaf(y[j], y[j], sq[j]);
        }
    }

    __shared__ float sred[32][8];
#pragma unroll
    for (int q = 0; q < 8; ++q) {
        float v = (q < 4) ? s[q] : sq[q - 4];
        sred[lane][grp] = v;
        __syncthreads();
        if (grp == 0) {
            float t = 0.f;
#pragma unroll
            for (int g = 0; g < 8; ++g) t += sred[lane][g];
            int f = fq + (q & 3);
            atomicAdd(stats + ((q < 4) ? f : 128 + f), t);
        }
        __syncthreads();
    }
}

// finalize F=64: y fp32 -> out
__global__ __launch_bounds__(256) void finalize64_kernel(
    const unsigned short* __restrict__ hs, const float* __restrict__ acc,
    const float* __restrict__ dinv, const float* __restrict__ bias,
    float* __restrict__ out, int n) {
    const int lane = threadIdx.x & 15;   // 16 lanes x 4 feats
    const int grp = threadIdx.x >> 4;    // 16 rows per pass
    const int fq = lane * 4;
    const float4 b4 = *reinterpret_cast<const float4*>(bias + fq);
    for (int i = blockIdx.x * 16 + grp; i < n; i += gridDim.x * 16) {
        const float di = dinv[i];
        uint2 hv = *reinterpret_cast<const uint2*>(hs + (size_t)i * 64 + fq);
        float4 av = *reinterpret_cast<const float4*>(acc + (size_t)i * 64 + fq);
        float4 y;
        y.x = fmaf(di, bf2f_lo(hv.x) + av.x, b4.x);
        y.y = fmaf(di, bf2f_hi(hv.x) + av.y, b4.y);
        y.z = fmaf(di, bf2f_lo(hv.y) + av.z, b4.z);
        y.w = fmaf(di, bf2f_hi(hv.y) + av.w, b4.w);
        *reinterpret_cast<float4*>(out + (size_t)i * 64 + fq) = y;
    }
}

// ================= OLD PATH (r2, byte-exact) machinery =================

__global__ __launch_bounds__(256) void prescan_kernel(
    const int* __restrict__ deg, int n, int B, float* __restrict__ dinv,
    int* __restrict__ bh, int* __restrict__ rowptr, int* __restrict__ bsum) {
    __shared__ int lh[64];
    __shared__ int sh[256];
    const int t = threadIdx.x, b = blockIdx.x;
    if (t < 64) lh[t] = 0;
    __syncthreads();
    const int base = b * 2048 + t * 8;
    int v[8];
    int run = 0;
#pragma unroll
    for (int j = 0; j < 8; ++j) {
        int idx = base + j;
        int d = 0;
        if (idx < n) {
            d = deg[idx];
            dinv[idx] = rsqrtf((float)(d + 1));
            atomicAdd(&lh[min(d, 63)], 1);
        }
        run += d;
        v[j] = run;
    }
    sh[t] = run;
    __syncthreads();
#pragma unroll
    for (int off = 1; off < 256; off <<= 1) {
        int add = (t >= off) ? sh[t - off] : 0;
        __syncthreads();
        sh[t] += add;
        __syncthreads();
    }
    int prev = (t > 0) ? sh[t - 1] : 0;
#pragma unroll
    for (int j = 0; j < 8; ++j) {
        int idx = base + j;
        if (idx < n) rowptr[idx + 1] = v[j] + prev;
    }
    if (t == 255) bsum[b] = sh[255];
    if (b == 0 && t == 0) rowptr[0] = 0;
    if (t < 64) bh[t * B + b] = lh[t];
}

__global__ void midscan_kernel(int* __restrict__ bh, int totalbh,
                               int* __restrict__ bsum, int B) {
    __shared__ int sh[256];
    const int t = threadIdx.x;
    int base = 0;
    for (int start = 0; start < totalbh; start += 256) {
        int i = start + t;
        int v = (i < totalbh) ? bh[i] : 0;
        sh[t] = v;
        __syncthreads();
#pragma unroll
        for (int off = 1; off < 256; off <<= 1) {
            int add = (t >= off) ? sh[t - off] : 0;
            __syncthreads();
            sh[t] += add;
            __syncthreads();
        }
        int excl = (t > 0 ? sh[t - 1] : 0) + base;
        if (i < totalbh) bh[i] = excl;
        base += sh[255];
        __syncthreads();
    }
    int v = (t < B) ? bsum[t] : 0;
    sh[t] = v;
    __syncthreads();
#pragma unroll
    for (int off = 1; off < 64; off <<= 1) {
        int add = (t >= off && t < 64) ? sh[t - off] : 0;
        __syncthreads();
        if (t < 64) sh[t] += add;
        __syncthreads();
    }
    if (t < B) bsum[t] = sh[t];
}

__global__ void place_scanC_kernel(const int* __restrict__ deg, int n, int B,
                                   const int* __restrict__ bh,
                                   const int* __restrict__ bsum,
                                   int* __restrict__ perm,
                                   int* __restrict__ rowptr) {
    const int t = threadIdx.x;
    if ((int)blockIdx.x < B) {
        const int b = blockIdx.x;
        __shared__ int lbase[64];
        __shared__ int lcur[64];
        if (t < 64) {
            lbase[t] = bh[t * B + b];
            lcur[t] = 0;
        }
        __syncthreads();
        const int lim = min((b + 1) * 2048, n);
        for (int i = b * 2048 + t; i < lim; i += 256) {
            int d = min(deg[i], 63);
            int r = atomicAdd(&lcur[d], 1);
            perm[lbase[d] + r] = i;
        }
    } else {
        const int c = blockIdx.x - B;
        if (c == 0) return;
        const int off = bsum[c - 1];
        const int lim = min((c + 1) * 2048, n);
        for (int i = c * 2048 + t; i < lim; i += 256) rowptr[i + 1] += off;
    }
}

__global__ void csr_build_kernel(const int* __restrict__ src,
                                 const int* __restrict__ dst, int E,
                                 int* __restrict__ rowptr,
                                 int* __restrict__ csr_src) {
    int e = blockIdx.x * blockDim.x + threadIdx.x;
    if (e < E) {
        int pos = atomicAdd(rowptr + dst[e], 1);
        csr_src[pos] = src[e];
    }
}

template <int F, bool STATS, bool OBF, bool SPLIT>
__global__ __launch_bounds__(256) void aggregate_kernel(
    const unsigned short* __restrict__ hs, const int* __restrict__ csr_src,
    const int* __restrict__ rowptr, const int* __restrict__ perm,
    const float* __restrict__ dinv, const float* __restrict__ bias,
    void* __restrict__ outp, int n, float* __restrict__ stats) {
    constexpr int FH = SPLIT ? (F / 2) : F;
    constexpr int LANES = FH / 4;
    constexpr int GROUPS = 256 / LANES;
    int wb = blockIdx.x;
    int nw = gridDim.x;
    int hb = 0;
    if (SPLIT) {
        const int xcd = wb & 7;
        hb = (xcd >= 4) ? (F / 2) : 0;
        wb = (wb >> 3) * 4 + (xcd & 3);
        nw = (nw >> 3) * 4;
    }
    const int lane = threadIdx.x % LANES;
    const int grp = threadIdx.x / LANES;
    const int fq = hb + lane * 4;
    const float4 b4 = *reinterpret_cast<const float4*>(bias + fq);
    float s[4] = {}, sq[4] = {};

    const int stride = nw * GROUPS * 4;

    for (int j0 = (wb * GROUPS + grp) * 4; j0 < n; j0 += stride) {
        const int nv = min(4, n - j0);
        int nd[4], e[4], end[4];
        float acc[4][4] = {};
#pragma unroll
        for (int q = 0; q < 4; ++q) {
            if (q < nv) {
                int node = perm[j0 + q];
                nd[q] = node;
                e[q] = (node == 0) ? 0 : rowptr[node - 1];
                end[q] = rowptr[node];
            } else {
                nd[q] = -1; e[q] = 0; end[q] = 0;
            }
        }
#pragma unroll
        for (int q = 0; q < 4; ++q)
            if (nd[q] >= 0)
                bf4_acc(*reinterpret_cast<const uint2*>(hs + (size_t)nd[q] * F + fq), acc[q]);
        int rem = end[0] - e[0];
#pragma unroll
        for (int q = 1; q < 4; ++q)
            if (q < nv) rem = min(rem, end[q] - e[q]);
        for (; rem >= 2; rem -= 2) {
            int i0[4], i1[4];
#pragma unroll
            for (int q = 0; q < 4; ++q) {
                i0[q] = csr_src[e[q]];
                i1[q] = csr_src[e[q] + 1];
                e[q] += 2;
            }
            uint2 v0[4], v1[4];
#pragma unroll
            for (int q = 0; q < 4; ++q) {
                v0[q] = *reinterpret_cast<const uint2*>(hs + (size_t)i0[q] * F + fq);
                v1[q] = *reinterpret_cast<const uint2*>(hs + (size_t)i1[q] * F + fq);
            }
#pragma unroll
            for (int q = 0; q < 4; ++q) {
                bf4_acc(v0[q], acc[q]);
                bf4_acc(v1[q], acc[q]);
            }
        }
#pragma unroll
        for (int q = 0; q < 4; ++q) {
            for (; e[q] < end[q]; ++e[q]) {
                int s0 = csr_src[e[q]];
                bf4_acc(*reinterpret_cast<const uint2*>(hs + (size_t)s0 * F + fq), acc[q]);
            }
        }
#pragma unroll
        for (int q = 0; q < 4; ++q) {
            if (nd[q] < 0) continue;
            const float di = dinv[nd[q]];
            float y[4];
            y[0] = fmaf(di, acc[q][0], b4.x);
            y[1] = fmaf(di, acc[q][1], b4.y);
            y[2] = fmaf(di, acc[q][2], b4.z);
            y[3] = fmaf(di, acc[q][3], b4.w);
            if (OBF) {
                uint2 p;
                p.x = f2bf(y[0]) | ((unsigned)f2bf(y[1]) << 16);
                p.y = f2bf(y[2]) | ((unsigned)f2bf(y[3]) << 16);
                *reinterpret_cast<uint2*>((unsigned short*)outp + (size_t)nd[q] * F + fq) = p;
            } else {
                *reinterpret_cast<float4*>((float*)outp + (size_t)nd[q] * F + fq) =
                    make_float4(y[0], y[1], y[2], y[3]);
            }
            if (STATS) {
#pragma unroll
                for (int j = 0; j < 4; ++j) {
                    s[j] += y[j];
                    sq[j] = fmaf(y[j], y[j], sq[j]);
                }
            }
        }
    }

    if (STATS) {
        __shared__ float sred[LANES][GROUPS + 1];
#pragma unroll
        for (int q = 0; q < 8; ++q) {
            float v = (q < 4) ? s[q] : sq[q - 4];
            sred[lane][grp] = v;
            __syncthreads();
            if (grp == 0) {
                float t = 0.f;
#pragma unroll
                for (int g = 0; g < GROUPS; ++g) t += sred[lane][g];
                int f = fq + (q & 3);
                atomicAdd(stats + ((q < 4) ? f : 128 + f), t);
            }
            __syncthreads();
        }
    }
}

// ================= GEMM (shared; optional acc-zero fold) =================
template <int NC, bool BN>
__global__ __launch_bounds__(256) void gemm_mfma(
    const unsigned short* __restrict__ A, const unsigned short* __restrict__ Wt,
    unsigned short* __restrict__ C, int n, const float* __restrict__ stats,
    const float* __restrict__ g, const float* __restrict__ be, float invn,
    const float* __restrict__ dinv, float* __restrict__ zacc, int zf4) {
    __shared__ unsigned short Asd[64][136];   // +8 pad: 2-way bank (free)
    __shared__ unsigned short Bsd[64][136];
    __shared__ float ssl[256];
    const int tid = threadIdx.x;
    const int wave = tid >> 6;
    const int lane = tid & 63;
    const int row0 = blockIdx.x * 64;
    const int col0 = blockIdx.y * 64;

    if (zacc != nullptr) {   // fold next-stage acc zeroing (r19)
        const int nb = gridDim.x * gridDim.y;
        const int bid = blockIdx.y * gridDim.x + blockIdx.x;
        const int per = (zf4 + nb - 1) / nb;
        const int st = bid * per;
        const int en = min(st + per, zf4);
        float4 z = make_float4(0.f, 0.f, 0.f, 0.f);
        for (int i = st + tid; i < en; i += 256)
            reinterpret_cast<float4*>(zacc)[i] = z;
    }

    if (BN) {
        if (tid < 128) {
            float mean = stats[tid] * invn;
            float var = fmaf(-mean, mean, stats[128 + tid] * invn);
            float sc = g[tid] * rsqrtf(var + 1e-5f);
            ssl[tid] = sc;
            ssl[128 + tid] = fmaf(-mean, sc, be[tid]);
        }
        __syncthreads();
    }

    for (int idx = tid; idx < 64 * 16; idx += 256) {
        int r = idx >> 4;
        int c = (idx & 15) * 8;
        uint4 v = *reinterpret_cast<const uint4*>(Wt + (size_t)(col0 + r) * 128 + c);
        *reinterpret_cast<uint4*>(&Bsd[r][c]) = v;
    }
    for (int idx = tid; idx < 64 * 16; idx += 256) {
        int r = idx >> 4;
        int c = (idx & 15) * 8;
        int grow = row0 + r;
        uint4 v = make_uint4(0u, 0u, 0u, 0u);
        if (grow < n)
            v = *reinterpret_cast<const uint4*>(A + (size_t)grow * 128 + c);
        if (BN) {
            unsigned int p[4] = {v.x, v.y, v.z, v.w};
#pragma unroll
            for (int h = 0; h < 4; ++h) {
                int f = c + h * 2;
                float lo = fmaxf(fmaf(bf2f_lo(p[h]), ssl[f], ssl[128 + f]), 0.f);
                float hi = fmaxf(fmaf(bf2f_hi(p[h]), ssl[f + 1], ssl[129 + f]), 0.f);
                p[h] = f2bf(lo) | ((unsigned)f2bf(hi) << 16);
            }
            v = make_uint4(p[0], p[1], p[2], p[3]);
        }
        *reinterpret_cast<uint4*>(&Asd[r][c]) = v;
    }
    __syncthreads();

    f32x4 acc[4];
#pragma unroll
    for (int t = 0; t < 4; ++t) acc[t] = (f32x4)(0.f);

    const int l15 = lane & 15;
    const int quad = lane >> 4;
#pragma unroll
    for (int kb = 0; kb < 128; kb += 32) {
        short8 a = *reinterpret_cast<const short8*>(&Asd[wave * 16 + l15][kb + quad * 8]);
#pragma unroll
        for (int t = 0; t < 4; ++t) {
            short8 b = *reinterpret_cast<const short8*>(&Bsd[t * 16 + l15][kb + quad * 8]);
            acc[t] = __builtin_amdgcn_mfma_f32_16x16x32_bf16(a, b, acc[t], 0, 0, 0);
        }
    }

    const int rbase = row0 + wave * 16 + quad * 4;
    float dv[4] = {0.f, 0.f, 0.f, 0.f};
    if (rbase < n) {  // dinv padded by +64 in ws
        float4 d4 = *reinterpret_cast<const float4*>(dinv + rbase);
        dv[0] = d4.x; dv[1] = d4.y; dv[2] = d4.z; dv[3] = d4.w;
    }
#pragma unroll
    for (int t = 0; t < 4; ++t) {
        int col = col0 + t * 16 + l15;
#pragma unroll
        for (int r = 0; r < 4; ++r) {
            int row = rbase + r;
            if (row < n)
                C[(size_t)row * NC + col] = f2bf(acc[t][r] * dv[r]);
        }
    }
}

extern "C" void kernel_launch(void* const* d_in, const int* in_sizes, int n_in,
                              void* d_out, int out_size, void* d_ws,
                              size_t ws_size, hipStream_t stream) {
    const float* x   = (const float*)d_in[0];
    const int*   ei  = (const int*)d_in[1];
    const float* W1  = (const float*)d_in[2];
    const float* b1  = (const float*)d_in[3];
    const float* g1  = (const float*)d_in[4];
    const float* be1 = (const float*)d_in[5];
    const float* W2  = (const float*)d_in[6];
    const float* b2  = (const float*)d_in[7];
    const float* g2  = (const float*)d_in[8];
    const float* be2 = (const float*)d_in[9];
    const float* W3  = (const float*)d_in[10];
    const float* b3  = (const float*)d_in[11];
    float* out = (float*)d_out;

    const int n = in_sizes[0] / 128;
    const int E = in_sizes[1] / 2;
    const int* src = ei;
    const int* dst = ei + E;

    const int B = (n + 2047) / 2048;
    const int EB = (E + 255) / 256;
    const int total4 = n * 32;
    const int XB = (total4 + 255) / 256;
    const int gemmRows = (n + 63) / 64;
    dim3 gemmGrid128(gemmRows, 2);
    dim3 gemmGrid64(gemmRows, 1);
    const float invn = 1.0f / n;

    // ---- r19 layout (only used if ws is large enough) ----
    float* wsf    = (float*)d_ws;
    float* stats1 = wsf;                          // 256
    float* stats2 = stats1 + 256;                 // 256
    int*   deg    = (int*)(stats2 + 256);         // n
    int*   sdeg   = deg + n;                      // n
    float* dinv   = (float*)(sdeg + n);           // n + 64
    int*   bsum   = (int*)(dinv + n + 64);        // 64
    int*   srcptr = bsum + 64;                    // n + 4 (n+1 used)
    int*   cscdst = srcptr + (n + 4);             // E
    unsigned short* wt1  = (unsigned short*)(cscdst + E);     // 128*128
    unsigned short* wt2  = wt1 + 128 * 128;
    unsigned short* wt3  = wt2 + 128 * 128;                   // 64*128
    unsigned short* abuf = wt3 + 64 * 128;                    // n*128 bf16
    unsigned short* hsb  = abuf + (size_t)n * 128;            // n*128 bf16
    float* acc = (float*)(hsb + (size_t)n * 128);             // n*128 fp32
    size_t need_new = (size_t)((char*)(acc + (size_t)n * 128) - (char*)d_ws);

    if (ws_size >= need_new) {
        // ======== r19 scatter path ========
        hipMemsetAsync(wsf, 0, (size_t)(512 + 2 * n) * 4, stream);  // stats+deg+sdeg
        prep_kernel<<<EB + XB + 160, 256, 0, stream>>>(src, dst, E, deg, sdeg,
                                                       x, abuf, total4,
                                                       W1, W2, W3, wt1, wt2, wt3,
                                                       EB, XB);
        prescan2_kernel<<<B, 256, 0, stream>>>(deg, sdeg, n, dinv, srcptr, bsum);
        midscan2_kernel<<<1, 64, 0, stream>>>(bsum, B);
        fixup_kernel<<<B, 256, 0, stream>>>(n, bsum, srcptr);
        csc_build_kernel<<<EB, 256, 0, stream>>>(src, dst, E, srcptr, cscdst);

        // ---- layer 1 ----
        gemm_mfma<128, false><<<gemmGrid128, 256, 0, stream>>>(
            abuf, wt1, hsb, n, nullptr, nullptr, nullptr, invn, dinv, acc, n * 32);
        scatter_kernel<128><<<1024, 256, 0, stream>>>(hsb, srcptr, cscdst, acc, n, E);
        finalize128_kernel<<<512, 256, 0, stream>>>(hsb, acc, dinv, b1, abuf, n, stats1);
        // ---- layer 2 ----
        gemm_mfma<128, true><<<gemmGrid128, 256, 0, stream>>>(
            abuf, wt2, hsb, n, stats1, g1, be1, invn, dinv, acc, n * 32);
        scatter_kernel<128><<<1024, 256, 0, stream>>>(hsb, srcptr, cscdst, acc, n, E);
        finalize128_kernel<<<512, 256, 0, stream>>>(hsb, acc, dinv, b2, abuf, n, stats2);
        // ---- layer 3 ----
        gemm_mfma<64, true><<<gemmGrid64, 256, 0, stream>>>(
            abuf, wt3, hsb, n, stats2, g2, be2, invn, dinv, acc, n * 16);
        scatter_kernel<64><<<1024, 256, 0, stream>>>(hsb, srcptr, cscdst, acc, n, E);
        finalize64_kernel<<<512, 256, 0, stream>>>(hsb, acc, dinv, b3, out, n);
        return;
    }

    // ======== r2 gather path (byte-exact r2 layout; known-good 393us) ========
    int*   odeg   = (int*)(stats2 + 256);         // n
    float* odinv  = (float*)(odeg + n);           // n + 64
    int*   obh    = (int*)(odinv + n + 64);       // 64*32
    int*   obsum  = obh + 64 * 32;                // 64
    int*   orowp  = obsum + 64;                   // n+1
    int*   operm  = orowp + (n + 1);              // n
    int*   ocsr   = operm + n;                    // E
    unsigned short* owt1 = (unsigned short*)(ocsr + E);
    unsigned short* owt2 = owt1 + 128 * 128;
    unsigned short* owt3 = owt2 + 128 * 128;
    unsigned short* oab  = owt3 + 64 * 128;
    unsigned short* ohs  = oab + (size_t)n * 128;

    hipMemsetAsync(wsf, 0, (size_t)(512 + n) * 4, stream);   // stats + deg only
    prep_kernel<<<EB + XB + 160, 256, 0, stream>>>(src, dst, E, odeg, nullptr,
                                                   x, oab, total4,
                                                   W1, W2, W3, owt1, owt2, owt3,
                                                   EB, XB);
    prescan_kernel<<<B, 256, 0, stream>>>(odeg, n, B, odinv, obh, orowp, obsum);
    midscan_kernel<<<1, 256, 0, stream>>>(obh, 64 * B, obsum, B);
    place_scanC_kernel<<<2 * B, 256, 0, stream>>>(odeg, n, B, obh, obsum, operm, orowp);
    csr_build_kernel<<<EB, 256, 0, stream>>>(src, dst, E, orowp, ocsr);

    const int aggGrid = 512;
    gemm_mfma<128, false><<<gemmGrid128, 256, 0, stream>>>(
        oab, owt1, ohs, n, nullptr, nullptr, nullptr, invn, odinv, nullptr, 0);
    aggregate_kernel<128, true, true, true><<<aggGrid, 256, 0, stream>>>(
        ohs, ocsr, orowp, operm, odinv, b1, oab, n, stats1);
    gemm_mfma<128, true><<<gemmGrid128, 256, 0, stream>>>(
        oab, owt2, ohs, n, stats1, g1, be1, invn, odinv, nullptr, 0);
    aggregate_kernel<128, true, true, true><<<aggGrid, 256, 0, stream>>>(
        ohs, ocsr, orowp, operm, odinv, b2, oab, n, stats2);
    gemm_mfma<64, true><<<gemmGrid64, 256, 0, stream>>>(
        oab, owt3, ohs, n, stats2, g2, be2, invn, odinv, nullptr, 0);
    aggregate_kernel<64, false, false, false><<<aggGrid, 256, 0, stream>>>(
        ohs, ocsr, orowp, operm, odinv, b3, out, n, nullptr);
}

// Round 7
// 405.956 us; speedup vs baseline: 8.7917x; 8.7917x over previous
//
#include <hip/hip_runtime.h>
#include <hip/hip_bf16.h>

// 3-layer GCN: bf16-MFMA GEMMs + degree-sorted CSR gather-reduce.
//   hs = bf16( dinv[row] * (act(A) @ W) )     (MFMA GEMM, act = BN+ReLU fused)
//   y[i] = dinv[i]*(hs[i] + sum_{e: s->i} hs[s]) + b  (fp32 acc, bf16 out)
// Aggregate ledger:
//  r3-r13: gather ~93us plateau @512blk/4-node (256B rows).
//  r15: XCD-count invariant FETCH -> replication model refuted.
//  r16: XCD feature-split -> 76.8us. Win = single-128B-line requests + 2x
//       streams (BW 2.0 TB/s). Hit rate only 20% (LRU-theory 62%).
//  r17: 2x grid: BW flat -> random-line ceiling ~16-17 G lines/s. Closed.
//  r18: src-sorted adjacency: null (+50us sort tax). REVERTED.
//  r19/r20: partitioned scatter: CORRECT but 1285us/layer — 77M scalar
//       atomic RMWs (no HW coalescing, ~60G/s) + acc L2-thrash (WRITE 1.35GB).
//       Scatter closed permanently. ws_size >= 54.5MB confirmed.
//  r21: gather restored (r2-exact layout). A/B probe: L2-POLLUTION theory.
//       Every XCD streams the full csr_src (2.4MB) + perm/rowptr + output
//       writes through the 4MB L2 holding the 6.4MB hs hot-set -> streams
//       cycle the cache, explaining hit 20% vs 62%. agg1 = non-temporal
//       (nt) loads for csr/perm/rowptr + nt output stores; agg2 = control.
//       Predict agg1 FETCH 133->80-100MB, dur 77->58-68us; null -> pivot to
//       src-quartered sequential partials.

typedef __attribute__((ext_vector_type(8))) short short8;   // 8 bf16
typedef __attribute__((ext_vector_type(4))) float f32x4;    // 4 fp32 acc

__device__ inline unsigned short f2bf(float f) {  // round-to-nearest-even
    unsigned int u = __float_as_uint(f);
    return (unsigned short)((u + 0x7fff + ((u >> 16) & 1)) >> 16);
}
__device__ inline float bf2f_lo(unsigned int p) { return __uint_as_float(p << 16); }
__device__ inline float bf2f_hi(unsigned int p) { return __uint_as_float(p & 0xffff0000u); }

__device__ inline void bf4_acc(uint2 v, float* a) {
    a[0] += bf2f_lo(v.x); a[1] += bf2f_hi(v.x);
    a[2] += bf2f_lo(v.y); a[3] += bf2f_hi(v.y);
}

// ---- fused prep: deg count + x->bf16 + W->Wt bf16 (sdeg unused, nullable) ----
__global__ void prep_kernel(const int* __restrict__ src,
                            const int* __restrict__ dst, int E,
                            int* __restrict__ deg, int* __restrict__ sdeg,
                            const float* __restrict__ x,
                            unsigned short* __restrict__ xb, int total4,
                            const float* __restrict__ W1,
                            const float* __restrict__ W2,
                            const float* __restrict__ W3,
                            unsigned short* __restrict__ wt1,
                            unsigned short* __restrict__ wt2,
                            unsigned short* __restrict__ wt3,
                            int EB, int XB) {
    const int b = blockIdx.x;
    const int t = threadIdx.x;
    if (b < EB) {
        int e = b * 256 + t;
        if (e < E) {
            atomicAdd(deg + dst[e], 1);
            if (sdeg != nullptr) atomicAdd(sdeg + src[e], 1);
        }
    } else if (b < EB + XB) {
        int i = (b - EB) * 256 + t;
        if (i < total4) {
            float4 v = reinterpret_cast<const float4*>(x)[i];
            uint2 p;
            p.x = f2bf(v.x) | ((unsigned)f2bf(v.y) << 16);
            p.y = f2bf(v.z) | ((unsigned)f2bf(v.w) << 16);
            reinterpret_cast<uint2*>(xb)[i] = p;
        }
    } else if (b < EB + XB + 64) {
        int idx = (b - EB - XB) * 256 + t;   // 128x128
        int k = idx >> 7, nn = idx & 127;
        wt1[nn * 128 + k] = f2bf(W1[idx]);
    } else if (b < EB + XB + 128) {
        int idx = (b - EB - XB - 64) * 256 + t;
        int k = idx >> 7, nn = idx & 127;
        wt2[nn * 128 + k] = f2bf(W2[idx]);
    } else {
        int idx = (b - EB - XB - 128) * 256 + t;  // 128x64
        int k = idx >> 6, nn = idx & 63;
        wt3[nn * 128 + k] = f2bf(W3[idx]);
    }
}

// ---- fused: dinv + degree histogram + per-chunk rowptr prefix ----
__global__ __launch_bounds__(256) void prescan_kernel(
    const int* __restrict__ deg, int n, int B, float* __restrict__ dinv,
    int* __restrict__ bh, int* __restrict__ rowptr, int* __restrict__ bsum) {
    __shared__ int lh[64];
    __shared__ int sh[256];
    const int t = threadIdx.x, b = blockIdx.x;
    if (t < 64) lh[t] = 0;
    __syncthreads();
    const int base = b * 2048 + t * 8;
    int v[8];
    int run = 0;
#pragma unroll
    for (int j = 0; j < 8; ++j) {
        int idx = base + j;
        int d = 0;
        if (idx < n) {
            d = deg[idx];
            dinv[idx] = rsqrtf((float)(d + 1));
            atomicAdd(&lh[min(d, 63)], 1);
        }
        run += d;
        v[j] = run;
    }
    sh[t] = run;
    __syncthreads();
#pragma unroll
    for (int off = 1; off < 256; off <<= 1) {
        int add = (t >= off) ? sh[t - off] : 0;
        __syncthreads();
        sh[t] += add;
        __syncthreads();
    }
    int prev = (t > 0) ? sh[t - 1] : 0;
#pragma unroll
    for (int j = 0; j < 8; ++j) {
        int idx = base + j;
        if (idx < n) rowptr[idx + 1] = v[j] + prev;
    }
    if (t == 255) bsum[b] = sh[255];
    if (b == 0 && t == 0) rowptr[0] = 0;
    if (t < 64) bh[t * B + b] = lh[t];
}

// ---- fused single-block: excl scan bh[64*B] + incl scan bsum[B] ----
__global__ void midscan_kernel(int* __restrict__ bh, int totalbh,
                               int* __restrict__ bsum, int B) {
    __shared__ int sh[256];
    const int t = threadIdx.x;
    int base = 0;
    for (int start = 0; start < totalbh; start += 256) {
        int i = start + t;
        int v = (i < totalbh) ? bh[i] : 0;
        sh[t] = v;
        __syncthreads();
#pragma unroll
        for (int off = 1; off < 256; off <<= 1) {
            int add = (t >= off) ? sh[t - off] : 0;
            __syncthreads();
            sh[t] += add;
            __syncthreads();
        }
        int excl = (t > 0 ? sh[t - 1] : 0) + base;
        if (i < totalbh) bh[i] = excl;
        base += sh[255];
        __syncthreads();
    }
    int v = (t < B) ? bsum[t] : 0;
    sh[t] = v;
    __syncthreads();
#pragma unroll
    for (int off = 1; off < 64; off <<= 1) {
        int add = (t >= off && t < 64) ? sh[t - off] : 0;
        __syncthreads();
        if (t < 64) sh[t] += add;
        __syncthreads();
    }
    if (t < B) bsum[t] = sh[t];
}

// ---- fused: place (blocks 0..B-1) + rowptr chunk-offset add (B..2B-1) ----
__global__ void place_scanC_kernel(const int* __restrict__ deg, int n, int B,
                                   const int* __restrict__ bh,
                                   const int* __restrict__ bsum,
                                   int* __restrict__ perm,
                                   int* __restrict__ rowptr) {
    const int t = threadIdx.x;
    if ((int)blockIdx.x < B) {
        const int b = blockIdx.x;
        __shared__ int lbase[64];
        __shared__ int lcur[64];
        if (t < 64) {
            lbase[t] = bh[t * B + b];
            lcur[t] = 0;
        }
        __syncthreads();
        const int lim = min((b + 1) * 2048, n);
        for (int i = b * 2048 + t; i < lim; i += 256) {
            int d = min(deg[i], 63);
            int r = atomicAdd(&lcur[d], 1);
            perm[lbase[d] + r] = i;
        }
    } else {
        const int c = blockIdx.x - B;
        if (c == 0) return;
        const int off = bsum[c - 1];
        const int lim = min((c + 1) * 2048, n);
        for (int i = c * 2048 + t; i < lim; i += 256) rowptr[i + 1] += off;
    }
}

// destructive cursor CSR edge placement
__global__ void csr_build_kernel(const int* __restrict__ src,
                                 const int* __restrict__ dst, int E,
                                 int* __restrict__ rowptr,
                                 int* __restrict__ csr_src) {
    int e = blockIdx.x * blockDim.x + threadIdx.x;
    if (e < E) {
        int pos = atomicAdd(rowptr + dst[e], 1);
        csr_src[pos] = src[e];
    }
}

// Degree-sorted 4-node gather-reduce (r11 concurrency config).
// SPLIT (r16): XCDs 0-3 = features [0,F/2), XCDs 4-7 = [F/2,F).
// NT (r21): non-temporal loads for csr_src/perm/rowptr and nt output stores
// so the streams don't evict the hs hot-set from the XCD's L2.
template <int F, bool STATS, bool OBF, bool SPLIT, bool NT>
__global__ __launch_bounds__(256) void aggregate_kernel(
    const unsigned short* __restrict__ hs, const int* __restrict__ csr_src,
    const int* __restrict__ rowptr, const int* __restrict__ perm,
    const float* __restrict__ dinv, const float* __restrict__ bias,
    void* __restrict__ outp, int n, float* __restrict__ stats) {
    constexpr int FH = SPLIT ? (F / 2) : F;
    constexpr int LANES = FH / 4;
    constexpr int GROUPS = 256 / LANES;
    int wb = blockIdx.x;
    int nw = gridDim.x;
    int hb = 0;
    if (SPLIT) {
        const int xcd = wb & 7;
        hb = (xcd >= 4) ? (F / 2) : 0;
        wb = (wb >> 3) * 4 + (xcd & 3);
        nw = (nw >> 3) * 4;
    }
    const int lane = threadIdx.x % LANES;
    const int grp = threadIdx.x / LANES;
    const int fq = hb + lane * 4;
    const float4 b4 = *reinterpret_cast<const float4*>(bias + fq);
    float s[4] = {}, sq[4] = {};

    const int stride = nw * GROUPS * 4;

#define LDI(p) (NT ? __builtin_nontemporal_load(p) : *(p))

    for (int j0 = (wb * GROUPS + grp) * 4; j0 < n; j0 += stride) {
        const int nv = min(4, n - j0);
        int nd[4], e[4], end[4];
        float acc[4][4] = {};
#pragma unroll
        for (int q = 0; q < 4; ++q) {
            if (q < nv) {
                int node = LDI(perm + j0 + q);
                nd[q] = node;
                e[q] = (node == 0) ? 0 : LDI(rowptr + node - 1);
                end[q] = LDI(rowptr + node);
            } else {
                nd[q] = -1; e[q] = 0; end[q] = 0;
            }
        }
#pragma unroll
        for (int q = 0; q < 4; ++q)
            if (nd[q] >= 0)
                bf4_acc(*reinterpret_cast<const uint2*>(hs + (size_t)nd[q] * F + fq), acc[q]);
        int rem = end[0] - e[0];
#pragma unroll
        for (int q = 1; q < 4; ++q)
            if (q < nv) rem = min(rem, end[q] - e[q]);
        for (; rem >= 2; rem -= 2) {
            int i0[4], i1[4];
#pragma unroll
            for (int q = 0; q < 4; ++q) {
                i0[q] = LDI(csr_src + e[q]);
                i1[q] = LDI(csr_src + e[q] + 1);
                e[q] += 2;
            }
            uint2 v0[4], v1[4];
#pragma unroll
            for (int q = 0; q < 4; ++q) {
                v0[q] = *reinterpret_cast<const uint2*>(hs + (size_t)i0[q] * F + fq);
                v1[q] = *reinterpret_cast<const uint2*>(hs + (size_t)i1[q] * F + fq);
            }
#pragma unroll
            for (int q = 0; q < 4; ++q) {
                bf4_acc(v0[q], acc[q]);
                bf4_acc(v1[q], acc[q]);
            }
        }
#pragma unroll
        for (int q = 0; q < 4; ++q) {
            for (; e[q] < end[q]; ++e[q]) {
                int s0 = LDI(csr_src + e[q]);
                bf4_acc(*reinterpret_cast<const uint2*>(hs + (size_t)s0 * F + fq), acc[q]);
            }
        }
#pragma unroll
        for (int q = 0; q < 4; ++q) {
            if (nd[q] < 0) continue;
            const float di = dinv[nd[q]];
            float y[4];
            y[0] = fmaf(di, acc[q][0], b4.x);
            y[1] = fmaf(di, acc[q][1], b4.y);
            y[2] = fmaf(di, acc[q][2], b4.z);
            y[3] = fmaf(di, acc[q][3], b4.w);
            if (OBF) {
                uint2 p;
                p.x = f2bf(y[0]) | ((unsigned)f2bf(y[1]) << 16);
                p.y = f2bf(y[2]) | ((unsigned)f2bf(y[3]) << 16);
                unsigned short* dstp = (unsigned short*)outp + (size_t)nd[q] * F + fq;
                if (NT) {
                    unsigned long long pv =
                        ((unsigned long long)p.y << 32) | (unsigned long long)p.x;
                    __builtin_nontemporal_store(pv, reinterpret_cast<unsigned long long*>(dstp));
                } else {
                    *reinterpret_cast<uint2*>(dstp) = p;
                }
            } else {
                *reinterpret_cast<float4*>((float*)outp + (size_t)nd[q] * F + fq) =
                    make_float4(y[0], y[1], y[2], y[3]);
            }
            if (STATS) {
#pragma unroll
                for (int j = 0; j < 4; ++j) {
                    s[j] += y[j];
                    sq[j] = fmaf(y[j], y[j], sq[j]);
                }
            }
        }
    }
#undef LDI

    if (STATS) {
        __shared__ float sred[LANES][GROUPS + 1];
#pragma unroll
        for (int q = 0; q < 8; ++q) {
            float v = (q < 4) ? s[q] : sq[q - 4];
            sred[lane][grp] = v;
            __syncthreads();
            if (grp == 0) {
                float t = 0.f;
#pragma unroll
                for (int g = 0; g < GROUPS; ++g) t += sred[lane][g];
                int f = fq + (q & 3);
                atomicAdd(stats + ((q < 4) ? f : 128 + f), t);
            }
            __syncthreads();
        }
    }
}

// ================= GEMM =================
// C[n x NC] = bf16( dinv[row] * (act(A[n x 128]) @ W) ); BN finalize folded.
template <int NC, bool BN>
__global__ __launch_bounds__(256) void gemm_mfma(
    const unsigned short* __restrict__ A, const unsigned short* __restrict__ Wt,
    unsigned short* __restrict__ C, int n, const float* __restrict__ stats,
    const float* __restrict__ g, const float* __restrict__ be, float invn,
    const float* __restrict__ dinv) {
    __shared__ unsigned short Asd[64][136];   // +8 pad: 2-way bank (free)
    __shared__ unsigned short Bsd[64][136];
    __shared__ float ssl[256];
    const int tid = threadIdx.x;
    const int wave = tid >> 6;
    const int lane = tid & 63;
    const int row0 = blockIdx.x * 64;
    const int col0 = blockIdx.y * 64;

    if (BN) {
        if (tid < 128) {
            float mean = stats[tid] * invn;
            float var = fmaf(-mean, mean, stats[128 + tid] * invn);
            float sc = g[tid] * rsqrtf(var + 1e-5f);
            ssl[tid] = sc;
            ssl[128 + tid] = fmaf(-mean, sc, be[tid]);
        }
        __syncthreads();
    }

    for (int idx = tid; idx < 64 * 16; idx += 256) {
        int r = idx >> 4;
        int c = (idx & 15) * 8;
        uint4 v = *reinterpret_cast<const uint4*>(Wt + (size_t)(col0 + r) * 128 + c);
        *reinterpret_cast<uint4*>(&Bsd[r][c]) = v;
    }
    for (int idx = tid; idx < 64 * 16; idx += 256) {
        int r = idx >> 4;
        int c = (idx & 15) * 8;
        int grow = row0 + r;
        uint4 v = make_uint4(0u, 0u, 0u, 0u);
        if (grow < n)
            v = *reinterpret_cast<const uint4*>(A + (size_t)grow * 128 + c);
        if (BN) {
            unsigned int p[4] = {v.x, v.y, v.z, v.w};
#pragma unroll
            for (int h = 0; h < 4; ++h) {
                int f = c + h * 2;
                float lo = fmaxf(fmaf(bf2f_lo(p[h]), ssl[f], ssl[128 + f]), 0.f);
                float hi = fmaxf(fmaf(bf2f_hi(p[h]), ssl[f + 1], ssl[129 + f]), 0.f);
                p[h] = f2bf(lo) | ((unsigned)f2bf(hi) << 16);
            }
            v = make_uint4(p[0], p[1], p[2], p[3]);
        }
        *reinterpret_cast<uint4*>(&Asd[r][c]) = v;
    }
    __syncthreads();

    f32x4 acc[4];
#pragma unroll
    for (int t = 0; t < 4; ++t) acc[t] = (f32x4)(0.f);

    const int l15 = lane & 15;
    const int quad = lane >> 4;
#pragma unroll
    for (int kb = 0; kb < 128; kb += 32) {
        short8 a = *reinterpret_cast<const short8*>(&Asd[wave * 16 + l15][kb + quad * 8]);
#pragma unroll
        for (int t = 0; t < 4; ++t) {
            short8 b = *reinterpret_cast<const short8*>(&Bsd[t * 16 + l15][kb + quad * 8]);
            acc[t] = __builtin_amdgcn_mfma_f32_16x16x32_bf16(a, b, acc[t], 0, 0, 0);
        }
    }

    const int rbase = row0 + wave * 16 + quad * 4;
    float dv[4] = {0.f, 0.f, 0.f, 0.f};
    if (rbase < n) {  // dinv padded by +64 in ws
        float4 d4 = *reinterpret_cast<const float4*>(dinv + rbase);
        dv[0] = d4.x; dv[1] = d4.y; dv[2] = d4.z; dv[3] = d4.w;
    }
#pragma unroll
    for (int t = 0; t < 4; ++t) {
        int col = col0 + t * 16 + l15;
#pragma unroll
        for (int r = 0; r < 4; ++r) {
            int row = rbase + r;
            if (row < n)
                C[(size_t)row * NC + col] = f2bf(acc[t][r] * dv[r]);
        }
    }
}

extern "C" void kernel_launch(void* const* d_in, const int* in_sizes, int n_in,
                              void* d_out, int out_size, void* d_ws,
                              size_t ws_size, hipStream_t stream) {
    const float* x   = (const float*)d_in[0];
    const int*   ei  = (const int*)d_in[1];
    const float* W1  = (const float*)d_in[2];
    const float* b1  = (const float*)d_in[3];
    const float* g1  = (const float*)d_in[4];
    const float* be1 = (const float*)d_in[5];
    const float* W2  = (const float*)d_in[6];
    const float* b2  = (const float*)d_in[7];
    const float* g2  = (const float*)d_in[8];
    const float* be2 = (const float*)d_in[9];
    const float* W3  = (const float*)d_in[10];
    const float* b3  = (const float*)d_in[11];
    float* out = (float*)d_out;

    const int n = in_sizes[0] / 128;
    const int E = in_sizes[1] / 2;
    const int* src = ei;
    const int* dst = ei + E;

    const int B = (n + 2047) / 2048;             // sort/scan chunks (25)
    const int EB = (E + 255) / 256;
    const int total4 = n * 32;
    const int XB = (total4 + 255) / 256;
    const int gemmRows = (n + 63) / 64;
    dim3 gemmGrid128(gemmRows, 2);
    dim3 gemmGrid64(gemmRows, 1);
    const float invn = 1.0f / n;

    // ---- r2-exact layout (known-good 393us) ----
    float* wsf    = (float*)d_ws;
    float* stats1 = wsf;                         // 256
    float* stats2 = stats1 + 256;                // 256
    int*   deg    = (int*)(stats2 + 256);        // n
    float* dinv   = (float*)(deg + n);           // n + 64 (padded)
    int*   bh     = (int*)(dinv + n + 64);       // 64*B (<= 64*32)
    int*   bsum   = bh + 64 * 32;                // 64
    int*   rowptr = bsum + 64;                   // n+1
    int*   perm   = rowptr + (n + 1);            // n
    int*   csrsrc = perm + n;                    // E
    unsigned short* wt1 = (unsigned short*)(csrsrc + E);      // 128*128
    unsigned short* wt2 = wt1 + 128 * 128;                    // 128*128
    unsigned short* wt3 = wt2 + 128 * 128;                    // 64*128
    unsigned short* abuf = wt3 + 64 * 128;                    // n*128 bf16
    unsigned short* hsb  = abuf + (size_t)n * 128;            // n*128 bf16

    hipMemsetAsync(wsf, 0, (size_t)(512 + n) * 4, stream);
    prep_kernel<<<EB + XB + 160, 256, 0, stream>>>(src, dst, E, deg, nullptr,
                                                   x, abuf, total4,
                                                   W1, W2, W3, wt1, wt2, wt3,
                                                   EB, XB);
    prescan_kernel<<<B, 256, 0, stream>>>(deg, n, B, dinv, bh, rowptr, bsum);
    midscan_kernel<<<1, 256, 0, stream>>>(bh, 64 * B, bsum, B);
    place_scanC_kernel<<<2 * B, 256, 0, stream>>>(deg, n, B, bh, bsum, perm, rowptr);
    csr_build_kernel<<<EB, 256, 0, stream>>>(src, dst, E, rowptr, csrsrc);

    const int aggGrid = 512;                     // r11/r17 measured-best
    // ---- layer 1: NT probe ----
    gemm_mfma<128, false><<<gemmGrid128, 256, 0, stream>>>(
        abuf, wt1, hsb, n, nullptr, nullptr, nullptr, invn, dinv);
    aggregate_kernel<128, true, true, true, true><<<aggGrid, 256, 0, stream>>>(
        hsb, csrsrc, rowptr, perm, dinv, b1, abuf, n, stats1);
    // ---- layer 2: control ----
    gemm_mfma<128, true><<<gemmGrid128, 256, 0, stream>>>(
        abuf, wt2, hsb, n, stats1, g1, be1, invn, dinv);
    aggregate_kernel<128, true, true, true, false><<<aggGrid, 256, 0, stream>>>(
        hsb, csrsrc, rowptr, perm, dinv, b2, abuf, n, stats2);
    // ---- layer 3 ----
    gemm_mfma<64, true><<<gemmGrid64, 256, 0, stream>>>(
        abuf, wt3, hsb, n, stats2, g2, be2, invn, dinv);
    aggregate_kernel<64, false, false, false, false><<<aggGrid, 256, 0, stream>>>(
        hsb, csrsrc, rowptr, perm, dinv, b3, out, n, nullptr);
}